// Round 1
// baseline (1192.373 us; speedup 1.0000x reference)
//
#include <hip/hip_runtime.h>
#include <hip/hip_bf16.h>

// TransformerDecLayer on MI355X (gfx950).
// B=8, SQ=512, SK=1024, D=1024, H=16, DK=64, F=4096.
// All GEMMs: bf16 MFMA 16x16x32, 128x128 tile, global_load_lds(16B) staging (m97 pattern).
// Workspace layout (bytes, needs ~227MB):
//   0   xb      bf16 x            8MB
//   8   encb    bf16 enc_o        16MB
//   24  x1f     f32 LN1 out       16MB
//   40  x2f     f32 LN2 out       16MB
//   56  xcb     bf16 cur x        8MB
//   64  wT      bf16 W^T region   16MB (per-phase)
//   80  Qb      8MB
//   88  Kb      16MB
//   104 Vb      16MB
//   120 Vt      16MB  (V transposed per head: [B,H,DK,S])
//   136 Ob      8MB   (attn out, head-merged [B*Sq, D])
//   144 res     f32   16MB
//   160 Asf     bf16 self scores [B,H,512,512] 67MB; reused as FFN hidden 32MB

using bf16 = __hip_bfloat16;
typedef __attribute__((ext_vector_type(8))) short short8;
typedef __attribute__((ext_vector_type(4))) float f32x4;

#define DEVINL __device__ __forceinline__

DEVINL unsigned short bf16bits(float f) {
  __hip_bfloat16 h = __float2bfloat16(f);
  return *reinterpret_cast<unsigned short*>(&h);
}
DEVINL float bits2f(unsigned short u) {
  return __uint_as_float(((unsigned int)u) << 16);
}
DEVINL float tofloat(float f) { return f; }
DEVINL float tofloat(bf16 h) { return __bfloat162float(h); }

#define GLD16(gp, lp) __builtin_amdgcn_global_load_lds( \
    (__attribute__((address_space(1))) const void*)(gp), \
    (__attribute__((address_space(3))) void*)(lp), 16, 0, 0)

struct GemmP {
  const void* A; const bf16* Bt; void* C;
  const float* bias; const int* kmask;
  float scale;
  int M, N, K, lda, ldb, ldc;
  long sAb, sAh, sBb, sBh, sCb, sCh;  // element strides: base = (z>>4)*sXb + (z&15)*sXh
};

enum { EPI_BIAS_BF16 = 0, EPI_CAUSAL_BF16, EPI_KMASK_F32, EPI_NONE_BF16,
       EPI_BIAS_F32, EPI_BIAS_RELU_BF16 };

template<int EPI, bool AF32>
__global__ __launch_bounds__(256)
void gemm_k(GemmP p) {
  __shared__ bf16 As[128 * 32];
  __shared__ bf16 Bs[128 * 32];
  const int t = threadIdx.x;
  const int lane = t & 63;
  const int w = t >> 6;
  const int z = blockIdx.z;
  const int zb = z >> 4, zh = z & 15;
  const int m0 = blockIdx.y * 128, n0 = blockIdx.x * 128;

  const bf16* Bb = p.Bt + (long)zb * p.sBb + (long)zh * p.sBh;
  const int fl = lane & 15, fq = lane >> 4;
  const int wm = (w >> 1) * 64, wn = (w & 1) * 64;

  f32x4 acc[4][4];
#pragma unroll
  for (int i = 0; i < 4; ++i)
#pragma unroll
    for (int j = 0; j < 4; ++j) acc[i][j] = (f32x4){0.f, 0.f, 0.f, 0.f};

  const int sr = t >> 2;          // staging row 0..63
  const int sc = (t & 3) * 8;     // staging col (bf16 elems)
  char* ldsA = (char*)As + w * 1024;
  char* ldsB = (char*)Bs + w * 1024;

  int brow0 = n0 + sr;      if (brow0 > p.N - 1) brow0 = p.N - 1;
  int brow1 = n0 + sr + 64; if (brow1 > p.N - 1) brow1 = p.N - 1;

  const bf16* Ab16 = nullptr; const float* Af32 = nullptr;
  if (AF32) Af32 = (const float*)p.A + (long)zb * p.sAb + (long)zh * p.sAh;
  else      Ab16 = (const bf16*)p.A + (long)zb * p.sAb + (long)zh * p.sAh;

  for (int k0 = 0; k0 < p.K; k0 += 32) {
    if (!AF32) {
      GLD16(Ab16 + (long)(m0 + sr) * p.lda + k0 + sc, ldsA);
      GLD16(Ab16 + (long)(m0 + sr + 64) * p.lda + k0 + sc, ldsA + 4096);
    } else {
      // fp32 A (cross-attn probabilities): load, convert, ds_write
      const int ar = t >> 1, ac = (t & 1) * 16;
      const float* src = Af32 + (long)(m0 + ar) * p.lda + k0 + ac;
      float4 f0 = *(const float4*)(src);
      float4 f1 = *(const float4*)(src + 4);
      float4 f2 = *(const float4*)(src + 8);
      float4 f3 = *(const float4*)(src + 12);
      uint4 q0, q1;
      q0.x = bf16bits(f0.x) | ((unsigned)bf16bits(f0.y) << 16);
      q0.y = bf16bits(f0.z) | ((unsigned)bf16bits(f0.w) << 16);
      q0.z = bf16bits(f1.x) | ((unsigned)bf16bits(f1.y) << 16);
      q0.w = bf16bits(f1.z) | ((unsigned)bf16bits(f1.w) << 16);
      q1.x = bf16bits(f2.x) | ((unsigned)bf16bits(f2.y) << 16);
      q1.y = bf16bits(f2.z) | ((unsigned)bf16bits(f2.w) << 16);
      q1.z = bf16bits(f3.x) | ((unsigned)bf16bits(f3.y) << 16);
      q1.w = bf16bits(f3.z) | ((unsigned)bf16bits(f3.w) << 16);
      *(uint4*)(As + ar * 32 + ac) = q0;
      *(uint4*)(As + ar * 32 + ac + 8) = q1;
    }
    GLD16(Bb + (long)brow0 * p.ldb + k0 + sc, ldsB);
    GLD16(Bb + (long)brow1 * p.ldb + k0 + sc, ldsB + 4096);
    __syncthreads();

    short8 af[4], bfv[4];
#pragma unroll
    for (int i = 0; i < 4; ++i)
      af[i] = *(const short8*)(As + (wm + i * 16 + fl) * 32 + fq * 8);
#pragma unroll
    for (int j = 0; j < 4; ++j)
      bfv[j] = *(const short8*)(Bs + (wn + j * 16 + fl) * 32 + fq * 8);
#pragma unroll
    for (int i = 0; i < 4; ++i)
#pragma unroll
      for (int j = 0; j < 4; ++j)
        acc[i][j] = __builtin_amdgcn_mfma_f32_16x16x32_bf16(af[i], bfv[j], acc[i][j], 0, 0, 0);
    __syncthreads();
  }

  const float NEGINF = -__builtin_inff();
  const long cbase = (long)zb * p.sCb + (long)zh * p.sCh;
#pragma unroll
  for (int i = 0; i < 4; ++i) {
#pragma unroll
    for (int j = 0; j < 4; ++j) {
#pragma unroll
      for (int r = 0; r < 4; ++r) {
        int row = m0 + wm + i * 16 + fq * 4 + r;
        int col = n0 + wn + j * 16 + fl;
        if (col < p.N) {
          float v = acc[i][j][r];
          if (EPI == EPI_BIAS_BF16 || EPI == EPI_BIAS_F32 || EPI == EPI_BIAS_RELU_BF16)
            v += p.bias[col];
          if (EPI == EPI_BIAS_RELU_BF16) v = v > 0.f ? v : 0.f;
          if (EPI == EPI_CAUSAL_BF16) { v *= p.scale; if (col > row) v = NEGINF; }
          if (EPI == EPI_KMASK_F32)   { v *= p.scale; if (p.kmask[zb * 1024 + col] == 0) v = NEGINF; }
          long off = cbase + (long)row * p.ldc + col;
          if (EPI == EPI_KMASK_F32 || EPI == EPI_BIAS_F32) ((float*)p.C)[off] = v;
          else ((bf16*)p.C)[off] = __float2bfloat16(v);
        }
      }
    }
  }
}

// row softmax over 512 bf16 (self-attn scores), in place. 1 wave/row, 4 rows/block.
__global__ __launch_bounds__(256) void softmax_self_k(bf16* A) {
  const int lane = threadIdx.x & 63;
  const long row = (long)blockIdx.x * 4 + (threadIdx.x >> 6);
  bf16* p = A + row * 512;
  short8 raw = *(const short8*)(p + lane * 8);
  float v[8];
#pragma unroll
  for (int i = 0; i < 8; ++i) v[i] = bits2f((unsigned short)raw[i]);
  float mx = v[0];
#pragma unroll
  for (int i = 1; i < 8; ++i) mx = fmaxf(mx, v[i]);
  for (int off = 32; off; off >>= 1) mx = fmaxf(mx, __shfl_xor(mx, off, 64));
  float s = 0.f;
#pragma unroll
  for (int i = 0; i < 8; ++i) { v[i] = expf(v[i] - mx); s += v[i]; }
  for (int off = 32; off; off >>= 1) s += __shfl_xor(s, off, 64);
  float inv = 1.f / s;
  short8 o;
#pragma unroll
  for (int i = 0; i < 8; ++i) o[i] = (short)bf16bits(v[i] * inv);
  *(short8*)(p + lane * 8) = o;
}

// row softmax over 1024 f32 (cross-attn, lives in d_out), in place.
__global__ __launch_bounds__(256) void softmax_cross_k(float* A) {
  const int lane = threadIdx.x & 63;
  const long row = (long)blockIdx.x * 4 + (threadIdx.x >> 6);
  float* p = A + row * 1024;
  float4 v[4];
#pragma unroll
  for (int c = 0; c < 4; ++c) v[c] = *(const float4*)(p + c * 256 + lane * 4);
  float mx = v[0].x;
#pragma unroll
  for (int c = 0; c < 4; ++c) {
    mx = fmaxf(mx, v[c].x); mx = fmaxf(mx, v[c].y);
    mx = fmaxf(mx, v[c].z); mx = fmaxf(mx, v[c].w);
  }
  for (int off = 32; off; off >>= 1) mx = fmaxf(mx, __shfl_xor(mx, off, 64));
  float s = 0.f;
#pragma unroll
  for (int c = 0; c < 4; ++c) {
    v[c].x = expf(v[c].x - mx); s += v[c].x;
    v[c].y = expf(v[c].y - mx); s += v[c].y;
    v[c].z = expf(v[c].z - mx); s += v[c].z;
    v[c].w = expf(v[c].w - mx); s += v[c].w;
  }
  for (int off = 32; off; off >>= 1) s += __shfl_xor(s, off, 64);
  float inv = 1.f / s;
#pragma unroll
  for (int c = 0; c < 4; ++c) {
    v[c].x *= inv; v[c].y *= inv; v[c].z *= inv; v[c].w *= inv;
    *(float4*)(p + c * 256 + lane * 4) = v[c];
  }
}

// out = LN(x + r); writes f32 (outf) and optionally bf16 (outb). 1 wave/row of 1024.
__global__ __launch_bounds__(256)
void ln_k(const float* __restrict__ x, const float* __restrict__ r,
          const float* __restrict__ g, const float* __restrict__ bt,
          float* __restrict__ outf, bf16* __restrict__ outb) {
  const int lane = threadIdx.x & 63;
  const long row = (long)blockIdx.x * 4 + (threadIdx.x >> 6);
  const float* px = x + row * 1024;
  const float* pr = r + row * 1024;
  float4 v[4];
  float s = 0.f;
#pragma unroll
  for (int c = 0; c < 4; ++c) {
    float4 a = *(const float4*)(px + c * 256 + lane * 4);
    float4 b = *(const float4*)(pr + c * 256 + lane * 4);
    v[c].x = a.x + b.x; v[c].y = a.y + b.y; v[c].z = a.z + b.z; v[c].w = a.w + b.w;
    s += v[c].x + v[c].y + v[c].z + v[c].w;
  }
  for (int off = 32; off; off >>= 1) s += __shfl_xor(s, off, 64);
  float mu = s * (1.f / 1024.f);
  float q = 0.f;
#pragma unroll
  for (int c = 0; c < 4; ++c) {
    float dx = v[c].x - mu, dy = v[c].y - mu, dz = v[c].z - mu, dw = v[c].w - mu;
    q += dx * dx + dy * dy + dz * dz + dw * dw;
  }
  for (int off = 32; off; off >>= 1) q += __shfl_xor(q, off, 64);
  float rs = rsqrtf(q * (1.f / 1024.f) + 1e-5f);
#pragma unroll
  for (int c = 0; c < 4; ++c) {
    int col = c * 256 + lane * 4;
    float4 gg = *(const float4*)(g + col);
    float4 bb = *(const float4*)(bt + col);
    float4 o;
    o.x = (v[c].x - mu) * rs * gg.x + bb.x;
    o.y = (v[c].y - mu) * rs * gg.y + bb.y;
    o.z = (v[c].z - mu) * rs * gg.z + bb.z;
    o.w = (v[c].w - mu) * rs * gg.w + bb.w;
    *(float4*)(outf + row * 1024 + col) = o;
    if (outb) {
      uint2 pk;
      pk.x = bf16bits(o.x) | ((unsigned)bf16bits(o.y) << 16);
      pk.y = bf16bits(o.z) | ((unsigned)bf16bits(o.w) << 16);
      *(uint2*)(outb + row * 1024 + col) = pk;
    }
  }
}

// out[c*ldo + r] = bf16(in[r*ldi + c]); 32x32 LDS tiles, batched via grid.z (b,h strides).
template<typename TI>
__global__ __launch_bounds__(256)
void transpose_k(const TI* __restrict__ in, bf16* __restrict__ out,
                 int R, int C, int ldi, int ldo,
                 long sInb, long sInh, long sOutb, long sOuth) {
  __shared__ float tile[32][33];
  const int zb = blockIdx.z >> 4, zh = blockIdx.z & 15;
  const TI* pin = in + (long)zb * sInb + (long)zh * sInh;
  bf16* pout = out + (long)zb * sOutb + (long)zh * sOuth;
  const int c0 = blockIdx.x * 32, r0 = blockIdx.y * 32;
  const int tx = threadIdx.x & 31, ty = threadIdx.x >> 5;  // 32x8
#pragma unroll
  for (int i = 0; i < 32; i += 8)
    tile[ty + i][tx] = tofloat(pin[(long)(r0 + ty + i) * ldi + c0 + tx]);
  __syncthreads();
#pragma unroll
  for (int i = 0; i < 32; i += 8)
    pout[(long)(c0 + ty + i) * ldo + r0 + tx] = __float2bfloat16(tile[tx][ty + i]);
}

__global__ __launch_bounds__(256) void cvt_k(const float* __restrict__ in,
                                             bf16* __restrict__ out, long n4) {
  long i = (long)blockIdx.x * 256 + threadIdx.x;
  if (i < n4) {
    float4 v = *(const float4*)(in + i * 4);
    uint2 pk;
    pk.x = bf16bits(v.x) | ((unsigned)bf16bits(v.y) << 16);
    pk.y = bf16bits(v.z) | ((unsigned)bf16bits(v.w) << 16);
    *(uint2*)(out + i * 4) = pk;
  }
}

static inline GemmP mkp(const void* A, const bf16* Bt, void* C,
                        const float* bias, const int* km, float sc,
                        int M, int N, int K, int lda, int ldb, int ldc,
                        long sAb, long sAh, long sBb, long sBh, long sCb, long sCh) {
  GemmP p;
  p.A = A; p.Bt = Bt; p.C = C; p.bias = bias; p.kmask = km; p.scale = sc;
  p.M = M; p.N = N; p.K = K; p.lda = lda; p.ldb = ldb; p.ldc = ldc;
  p.sAb = sAb; p.sAh = sAh; p.sBb = sBb; p.sBh = sBh; p.sCb = sCb; p.sCh = sCh;
  return p;
}

extern "C" void kernel_launch(void* const* d_in, const int* in_sizes, int n_in,
                              void* d_out, int out_size, void* d_ws, size_t ws_size,
                              hipStream_t stream) {
  const float* x        = (const float*)d_in[0];
  const float* enc_o    = (const float*)d_in[1];
  const int*   enc_mask = (const int*)d_in[2];
  const float* a1_wq = (const float*)d_in[3];  const float* a1_bq = (const float*)d_in[4];
  const float* a1_wk = (const float*)d_in[5];  const float* a1_bk = (const float*)d_in[6];
  const float* a1_wv = (const float*)d_in[7];  const float* a1_bv = (const float*)d_in[8];
  const float* a1_wo = (const float*)d_in[9];  const float* a1_bo = (const float*)d_in[10];
  const float* a2_wq = (const float*)d_in[11]; const float* a2_bq = (const float*)d_in[12];
  const float* a2_wk = (const float*)d_in[13]; const float* a2_bk = (const float*)d_in[14];
  const float* a2_wv = (const float*)d_in[15]; const float* a2_bv = (const float*)d_in[16];
  const float* a2_wo = (const float*)d_in[17]; const float* a2_bo = (const float*)d_in[18];
  const float* ff_w1 = (const float*)d_in[19]; const float* ff_b1 = (const float*)d_in[20];
  const float* ff_w2 = (const float*)d_in[21]; const float* ff_b2 = (const float*)d_in[22];
  const float* ln1_g = (const float*)d_in[23]; const float* ln1_b = (const float*)d_in[24];
  const float* ln2_g = (const float*)d_in[25]; const float* ln2_b = (const float*)d_in[26];
  const float* ln3_g = (const float*)d_in[27]; const float* ln3_b = (const float*)d_in[28];

  const size_t MB = 1u << 20;
  char* w = (char*)d_ws;
  bf16*  xb   = (bf16*)(w + 0);
  bf16*  encb = (bf16*)(w + 8 * MB);
  float* x1f  = (float*)(w + 24 * MB);
  float* x2f  = (float*)(w + 40 * MB);
  bf16*  xcb  = (bf16*)(w + 56 * MB);
  bf16*  wT   = (bf16*)(w + 64 * MB);
  bf16*  Qb   = (bf16*)(w + 80 * MB);
  bf16*  Kb   = (bf16*)(w + 88 * MB);
  bf16*  Vb   = (bf16*)(w + 104 * MB);
  bf16*  Vt   = (bf16*)(w + 120 * MB);
  bf16*  Ob   = (bf16*)(w + 136 * MB);
  float* res  = (float*)(w + 144 * MB);
  bf16*  Asf  = (bf16*)(w + 160 * MB);

  float* out_x  = (float*)d_out;
  float* attn   = (float*)d_out + 4194304;  // [B,H,512,1024] f32

  const dim3 blk(256);

  // ---- inputs to bf16 ----
  cvt_k<<<4096, blk, 0, stream>>>(x, xb, 1048576);
  cvt_k<<<8192, blk, 0, stream>>>(enc_o, encb, 2097152);

  // ================= Phase 1: self attention =================
  {
    dim3 tg(32, 32, 1);
    transpose_k<float><<<tg, blk, 0, stream>>>(a1_wq, wT + 0,       1024, 1024, 1024, 1024, 0, 0, 0, 0);
    transpose_k<float><<<tg, blk, 0, stream>>>(a1_wk, wT + 1048576, 1024, 1024, 1024, 1024, 0, 0, 0, 0);
    transpose_k<float><<<tg, blk, 0, stream>>>(a1_wv, wT + 2097152, 1024, 1024, 1024, 1024, 0, 0, 0, 0);
    transpose_k<float><<<tg, blk, 0, stream>>>(a1_wo, wT + 3145728, 1024, 1024, 1024, 1024, 0, 0, 0, 0);
  }
  dim3 gq(8, 32, 1);  // M=4096, N=1024
  gemm_k<EPI_BIAS_BF16, false><<<gq, blk, 0, stream>>>(
      mkp(xb, wT + 0,       Qb, a1_bq, nullptr, 0.f, 4096, 1024, 1024, 1024, 1024, 1024, 0,0,0,0,0,0));
  gemm_k<EPI_BIAS_BF16, false><<<gq, blk, 0, stream>>>(
      mkp(xb, wT + 1048576, Kb, a1_bk, nullptr, 0.f, 4096, 1024, 1024, 1024, 1024, 1024, 0,0,0,0,0,0));
  gemm_k<EPI_BIAS_BF16, false><<<gq, blk, 0, stream>>>(
      mkp(xb, wT + 2097152, Vb, a1_bv, nullptr, 0.f, 4096, 1024, 1024, 1024, 1024, 1024, 0,0,0,0,0,0));

  // S = Q K^T / 8, causal, bf16 -> Asf [B,H,512,512]
  gemm_k<EPI_CAUSAL_BF16, false><<<dim3(4, 4, 128), blk, 0, stream>>>(
      mkp(Qb, Kb, Asf, nullptr, nullptr, 0.125f, 512, 512, 64, 1024, 1024, 512,
          524288, 64, 524288, 64, 4194304, 262144));
  softmax_self_k<<<16384, blk, 0, stream>>>(Asf);

  // V -> Vt [B,H,64,512]
  transpose_k<bf16><<<dim3(2, 16, 128), blk, 0, stream>>>(
      Vb, Vt, 512, 64, 1024, 512, 524288, 64, 524288, 32768);

  // O = A V -> Ob [4096,1024] head-merged
  gemm_k<EPI_NONE_BF16, false><<<dim3(1, 4, 128), blk, 0, stream>>>(
      mkp(Asf, Vt, Ob, nullptr, nullptr, 0.f, 512, 64, 512, 512, 512, 1024,
          4194304, 262144, 524288, 32768, 524288, 64));

  // res = O wo + bo (f32)
  gemm_k<EPI_BIAS_F32, false><<<gq, blk, 0, stream>>>(
      mkp(Ob, wT + 3145728, res, a1_bo, nullptr, 0.f, 4096, 1024, 1024, 1024, 1024, 1024, 0,0,0,0,0,0));

  ln_k<<<1024, blk, 0, stream>>>(x, res, ln1_g, ln1_b, x1f, xcb);

  // ================= Phase 2: cross attention =================
  {
    dim3 tg(32, 32, 1);
    transpose_k<float><<<tg, blk, 0, stream>>>(a2_wq, wT + 0,       1024, 1024, 1024, 1024, 0, 0, 0, 0);
    transpose_k<float><<<tg, blk, 0, stream>>>(a2_wk, wT + 1048576, 1024, 1024, 1024, 1024, 0, 0, 0, 0);
    transpose_k<float><<<tg, blk, 0, stream>>>(a2_wv, wT + 2097152, 1024, 1024, 1024, 1024, 0, 0, 0, 0);
    transpose_k<float><<<tg, blk, 0, stream>>>(a2_wo, wT + 3145728, 1024, 1024, 1024, 1024, 0, 0, 0, 0);
  }
  gemm_k<EPI_BIAS_BF16, false><<<gq, blk, 0, stream>>>(
      mkp(xcb, wT + 0, Qb, a2_bq, nullptr, 0.f, 4096, 1024, 1024, 1024, 1024, 1024, 0,0,0,0,0,0));
  dim3 ge(8, 64, 1);  // M=8192
  gemm_k<EPI_BIAS_BF16, false><<<ge, blk, 0, stream>>>(
      mkp(encb, wT + 1048576, Kb, a2_bk, nullptr, 0.f, 8192, 1024, 1024, 1024, 1024, 1024, 0,0,0,0,0,0));
  gemm_k<EPI_BIAS_BF16, false><<<ge, blk, 0, stream>>>(
      mkp(encb, wT + 2097152, Vb, a2_bv, nullptr, 0.f, 8192, 1024, 1024, 1024, 1024, 1024, 0,0,0,0,0,0));

  // S = Q K^T / 8, kv-mask, f32 -> attn (in d_out)
  gemm_k<EPI_KMASK_F32, false><<<dim3(8, 4, 128), blk, 0, stream>>>(
      mkp(Qb, Kb, attn, nullptr, enc_mask, 0.125f, 512, 1024, 64, 1024, 1024, 1024,
          524288, 64, 1048576, 64, 8388608, 524288));
  softmax_cross_k<<<16384, blk, 0, stream>>>(attn);

  // V -> Vt [B,H,64,1024]
  transpose_k<bf16><<<dim3(2, 32, 128), blk, 0, stream>>>(
      Vb, Vt, 1024, 64, 1024, 1024, 1048576, 64, 1048576, 65536);

  // O = A V (A is f32 attn in d_out) -> Ob
  gemm_k<EPI_NONE_BF16, true><<<dim3(1, 4, 128), blk, 0, stream>>>(
      mkp(attn, Vt, Ob, nullptr, nullptr, 0.f, 512, 64, 1024, 1024, 1024, 1024,
          8388608, 524288, 1048576, 65536, 524288, 64));

  gemm_k<EPI_BIAS_F32, false><<<gq, blk, 0, stream>>>(
      mkp(Ob, wT + 3145728, res, a2_bo, nullptr, 0.f, 4096, 1024, 1024, 1024, 1024, 1024, 0,0,0,0,0,0));

  ln_k<<<1024, blk, 0, stream>>>(x1f, res, ln2_g, ln2_b, x2f, xcb);

  // ================= Phase 3: FFN =================
  transpose_k<float><<<dim3(128, 32, 1), blk, 0, stream>>>(
      ff_w1, wT, 1024, 4096, 4096, 1024, 0, 0, 0, 0);                 // w1T [4096,1024]
  transpose_k<float><<<dim3(32, 128, 1), blk, 0, stream>>>(
      ff_w2, wT + 4194304, 4096, 1024, 1024, 4096, 0, 0, 0, 0);       // w2T [1024,4096]

  gemm_k<EPI_BIAS_RELU_BF16, false><<<dim3(32, 32, 1), blk, 0, stream>>>(
      mkp(xcb, wT, Asf, ff_b1, nullptr, 0.f, 4096, 4096, 1024, 1024, 1024, 4096, 0,0,0,0,0,0));
  gemm_k<EPI_BIAS_F32, false><<<gq, blk, 0, stream>>>(
      mkp(Asf, wT + 4194304, res, ff_b2, nullptr, 0.f, 4096, 1024, 4096, 4096, 4096, 1024, 0,0,0,0,0,0));

  ln_k<<<1024, blk, 0, stream>>>(x2f, res, ln3_g, ln3_b, out_x, nullptr);
}

// Round 2
// 1155.038 us; speedup vs baseline: 1.0323x; 1.0323x over previous
//
#include <hip/hip_runtime.h>
#include <hip/hip_bf16.h>

// TransformerDecLayer on MI355X (gfx950).
// B=8, SQ=512, SK=1024, D=1024, H=16, DK=64, F=4096.
// GEMMs: bf16 MFMA 16x16x32, 128x128 tile, global_load_lds(16B) staging (m97 pattern).
// R1: fused self-QKV (N=3072), fused cross-KV (N=2048), FFN2 split-K=4 + reduce,
//     bf16 prob sidecar so cross A*V uses the fast GLD16 path.
// Workspace (MB): 0 xb(8) | 8 encb(16) | 24 x1f(16) | 40 x2f(16) | 56 xcb(8)
//   64 wT(32, all weights^T bf16) | 96 biases(1) | 104 QKV/Qc(24) | 128 KVc(32)
//   160 Vt(16) | 176 Ob(8) | 184 res(16) | 200 part(64) | 264 Asf(67, reused FFN hidden)
//   332 Pb bf16 cross probs(134)  -> ~466MB total

using bf16 = __hip_bfloat16;
typedef __attribute__((ext_vector_type(8))) short short8;
typedef __attribute__((ext_vector_type(4))) float f32x4;

#define DEVINL __device__ __forceinline__

DEVINL unsigned short bf16bits(float f) {
  __hip_bfloat16 h = __float2bfloat16(f);
  return *reinterpret_cast<unsigned short*>(&h);
}
DEVINL float bits2f(unsigned short u) {
  return __uint_as_float(((unsigned int)u) << 16);
}
DEVINL float tofloat(float f) { return f; }
DEVINL float tofloat(bf16 h) { return __bfloat162float(h); }

#define GLD16(gp, lp) __builtin_amdgcn_global_load_lds( \
    (__attribute__((address_space(1))) const void*)(gp), \
    (__attribute__((address_space(3))) void*)(lp), 16, 0, 0)

struct GemmP {
  const bf16* A; const bf16* Bt; void* C;
  const float* bias; const int* kmask;
  float scale;
  int M, N, K, lda, ldb, ldc;
  long sAb, sAh, sBb, sBh, sCb, sCh;  // element strides: base = (z>>4)*sXb + (z&15)*sXh
};

enum { EPI_BIAS_BF16 = 0, EPI_CAUSAL_BF16, EPI_KMASK_F32, EPI_NONE_BF16,
       EPI_BIAS_F32, EPI_BIAS_RELU_BF16, EPI_PART_F32 };

template<int EPI>
__global__ __launch_bounds__(256)
void gemm_k(GemmP p) {
  __shared__ bf16 As[128 * 32];
  __shared__ bf16 Bs[128 * 32];
  const int t = threadIdx.x;
  const int lane = t & 63;
  const int w = t >> 6;
  const int z = blockIdx.z;
  const int zb = z >> 4, zh = z & 15;
  const int m0 = blockIdx.y * 128, n0 = blockIdx.x * 128;

  const bf16* Ab = p.A + (long)zb * p.sAb + (long)zh * p.sAh;
  const bf16* Bb = p.Bt + (long)zb * p.sBb + (long)zh * p.sBh;
  const int fl = lane & 15, fq = lane >> 4;
  const int wm = (w >> 1) * 64, wn = (w & 1) * 64;

  f32x4 acc[4][4];
#pragma unroll
  for (int i = 0; i < 4; ++i)
#pragma unroll
    for (int j = 0; j < 4; ++j) acc[i][j] = (f32x4){0.f, 0.f, 0.f, 0.f};

  const int sr = t >> 2;          // staging row 0..63
  const int sc = (t & 3) * 8;     // staging col (bf16 elems)
  char* ldsA = (char*)As + w * 1024;
  char* ldsB = (char*)Bs + w * 1024;

  int brow0 = n0 + sr;      if (brow0 > p.N - 1) brow0 = p.N - 1;
  int brow1 = n0 + sr + 64; if (brow1 > p.N - 1) brow1 = p.N - 1;

  for (int k0 = 0; k0 < p.K; k0 += 32) {
    GLD16(Ab + (long)(m0 + sr) * p.lda + k0 + sc, ldsA);
    GLD16(Ab + (long)(m0 + sr + 64) * p.lda + k0 + sc, ldsA + 4096);
    GLD16(Bb + (long)brow0 * p.ldb + k0 + sc, ldsB);
    GLD16(Bb + (long)brow1 * p.ldb + k0 + sc, ldsB + 4096);
    __syncthreads();

    short8 af[4], bfv[4];
#pragma unroll
    for (int i = 0; i < 4; ++i)
      af[i] = *(const short8*)(As + (wm + i * 16 + fl) * 32 + fq * 8);
#pragma unroll
    for (int j = 0; j < 4; ++j)
      bfv[j] = *(const short8*)(Bs + (wn + j * 16 + fl) * 32 + fq * 8);
#pragma unroll
    for (int i = 0; i < 4; ++i)
#pragma unroll
      for (int j = 0; j < 4; ++j)
        acc[i][j] = __builtin_amdgcn_mfma_f32_16x16x32_bf16(af[i], bfv[j], acc[i][j], 0, 0, 0);
    __syncthreads();
  }

  const float NEGINF = -__builtin_inff();
  const long cbase = (long)zb * p.sCb + (long)zh * p.sCh;
#pragma unroll
  for (int i = 0; i < 4; ++i) {
#pragma unroll
    for (int j = 0; j < 4; ++j) {
#pragma unroll
      for (int r = 0; r < 4; ++r) {
        int row = m0 + wm + i * 16 + fq * 4 + r;
        int col = n0 + wn + j * 16 + fl;
        if (col < p.N) {
          float v = acc[i][j][r];
          if (EPI == EPI_BIAS_BF16 || EPI == EPI_BIAS_F32 || EPI == EPI_BIAS_RELU_BF16)
            v += p.bias[col];
          if (EPI == EPI_BIAS_RELU_BF16) v = v > 0.f ? v : 0.f;
          if (EPI == EPI_CAUSAL_BF16) { v *= p.scale; if (col > row) v = NEGINF; }
          if (EPI == EPI_KMASK_F32)   { v *= p.scale; if (p.kmask[zb * 1024 + col] == 0) v = NEGINF; }
          long off = cbase + (long)row * p.ldc + col;
          if (EPI == EPI_KMASK_F32 || EPI == EPI_BIAS_F32 || EPI == EPI_PART_F32)
            ((float*)p.C)[off] = v;
          else ((bf16*)p.C)[off] = __float2bfloat16(v);
        }
      }
    }
  }
}

// row softmax over 512 bf16 (self-attn scores), in place. 1 wave/row, 4 rows/block.
__global__ __launch_bounds__(256) void softmax_self_k(bf16* A) {
  const int lane = threadIdx.x & 63;
  const long row = (long)blockIdx.x * 4 + (threadIdx.x >> 6);
  bf16* p = A + row * 512;
  short8 raw = *(const short8*)(p + lane * 8);
  float v[8];
#pragma unroll
  for (int i = 0; i < 8; ++i) v[i] = bits2f((unsigned short)raw[i]);
  float mx = v[0];
#pragma unroll
  for (int i = 1; i < 8; ++i) mx = fmaxf(mx, v[i]);
  for (int off = 32; off; off >>= 1) mx = fmaxf(mx, __shfl_xor(mx, off, 64));
  float s = 0.f;
#pragma unroll
  for (int i = 0; i < 8; ++i) { v[i] = expf(v[i] - mx); s += v[i]; }
  for (int off = 32; off; off >>= 1) s += __shfl_xor(s, off, 64);
  float inv = 1.f / s;
  short8 o;
#pragma unroll
  for (int i = 0; i < 8; ++i) o[i] = (short)bf16bits(v[i] * inv);
  *(short8*)(p + lane * 8) = o;
}

// row softmax over 1024 f32 (cross-attn, lives in d_out), in place; also writes bf16 copy.
__global__ __launch_bounds__(256) void softmax_cross_k(float* A, bf16* Pb) {
  const int lane = threadIdx.x & 63;
  const long row = (long)blockIdx.x * 4 + (threadIdx.x >> 6);
  float* p = A + row * 1024;
  float4 v[4];
#pragma unroll
  for (int c = 0; c < 4; ++c) v[c] = *(const float4*)(p + c * 256 + lane * 4);
  float mx = v[0].x;
#pragma unroll
  for (int c = 0; c < 4; ++c) {
    mx = fmaxf(mx, v[c].x); mx = fmaxf(mx, v[c].y);
    mx = fmaxf(mx, v[c].z); mx = fmaxf(mx, v[c].w);
  }
  for (int off = 32; off; off >>= 1) mx = fmaxf(mx, __shfl_xor(mx, off, 64));
  float s = 0.f;
#pragma unroll
  for (int c = 0; c < 4; ++c) {
    v[c].x = expf(v[c].x - mx); s += v[c].x;
    v[c].y = expf(v[c].y - mx); s += v[c].y;
    v[c].z = expf(v[c].z - mx); s += v[c].z;
    v[c].w = expf(v[c].w - mx); s += v[c].w;
  }
  for (int off = 32; off; off >>= 1) s += __shfl_xor(s, off, 64);
  float inv = 1.f / s;
#pragma unroll
  for (int c = 0; c < 4; ++c) {
    v[c].x *= inv; v[c].y *= inv; v[c].z *= inv; v[c].w *= inv;
    *(float4*)(p + c * 256 + lane * 4) = v[c];
    uint2 pk;
    pk.x = bf16bits(v[c].x) | ((unsigned)bf16bits(v[c].y) << 16);
    pk.y = bf16bits(v[c].z) | ((unsigned)bf16bits(v[c].w) << 16);
    *(uint2*)(Pb + row * 1024 + c * 256 + lane * 4) = pk;
  }
}

// out = LN(x + r); writes f32 (outf) and optionally bf16 (outb). 1 wave/row of 1024.
__global__ __launch_bounds__(256)
void ln_k(const float* __restrict__ x, const float* __restrict__ r,
          const float* __restrict__ g, const float* __restrict__ bt,
          float* __restrict__ outf, bf16* __restrict__ outb) {
  const int lane = threadIdx.x & 63;
  const long row = (long)blockIdx.x * 4 + (threadIdx.x >> 6);
  const float* px = x + row * 1024;
  const float* pr = r + row * 1024;
  float4 v[4];
  float s = 0.f;
#pragma unroll
  for (int c = 0; c < 4; ++c) {
    float4 a = *(const float4*)(px + c * 256 + lane * 4);
    float4 b = *(const float4*)(pr + c * 256 + lane * 4);
    v[c].x = a.x + b.x; v[c].y = a.y + b.y; v[c].z = a.z + b.z; v[c].w = a.w + b.w;
    s += v[c].x + v[c].y + v[c].z + v[c].w;
  }
  for (int off = 32; off; off >>= 1) s += __shfl_xor(s, off, 64);
  float mu = s * (1.f / 1024.f);
  float q = 0.f;
#pragma unroll
  for (int c = 0; c < 4; ++c) {
    float dx = v[c].x - mu, dy = v[c].y - mu, dz = v[c].z - mu, dw = v[c].w - mu;
    q += dx * dx + dy * dy + dz * dz + dw * dw;
  }
  for (int off = 32; off; off >>= 1) q += __shfl_xor(q, off, 64);
  float rs = rsqrtf(q * (1.f / 1024.f) + 1e-5f);
#pragma unroll
  for (int c = 0; c < 4; ++c) {
    int col = c * 256 + lane * 4;
    float4 gg = *(const float4*)(g + col);
    float4 bb = *(const float4*)(bt + col);
    float4 o;
    o.x = (v[c].x - mu) * rs * gg.x + bb.x;
    o.y = (v[c].y - mu) * rs * gg.y + bb.y;
    o.z = (v[c].z - mu) * rs * gg.z + bb.z;
    o.w = (v[c].w - mu) * rs * gg.w + bb.w;
    *(float4*)(outf + row * 1024 + col) = o;
    if (outb) {
      uint2 pk;
      pk.x = bf16bits(o.x) | ((unsigned)bf16bits(o.y) << 16);
      pk.y = bf16bits(o.z) | ((unsigned)bf16bits(o.w) << 16);
      *(uint2*)(outb + row * 1024 + col) = pk;
    }
  }
}

// out[c*ldo + r] = bf16(in[r*ldi + c]); 32x32 LDS tiles, batched via grid.z (b,h strides).
template<typename TI>
__global__ __launch_bounds__(256)
void transpose_k(const TI* __restrict__ in, bf16* __restrict__ out,
                 int R, int C, int ldi, int ldo,
                 long sInb, long sInh, long sOutb, long sOuth) {
  __shared__ float tile[32][33];
  const int zb = blockIdx.z >> 4, zh = blockIdx.z & 15;
  const TI* pin = in + (long)zb * sInb + (long)zh * sInh;
  bf16* pout = out + (long)zb * sOutb + (long)zh * sOuth;
  const int c0 = blockIdx.x * 32, r0 = blockIdx.y * 32;
  const int tx = threadIdx.x & 31, ty = threadIdx.x >> 5;  // 32x8
#pragma unroll
  for (int i = 0; i < 32; i += 8)
    tile[ty + i][tx] = tofloat(pin[(long)(r0 + ty + i) * ldi + c0 + tx]);
  __syncthreads();
#pragma unroll
  for (int i = 0; i < 32; i += 8)
    pout[(long)(c0 + ty + i) * ldo + r0 + tx] = __float2bfloat16(tile[tx][ty + i]);
}

__global__ __launch_bounds__(256) void cvt_k(const float* __restrict__ in,
                                             bf16* __restrict__ out, long n4) {
  long i = (long)blockIdx.x * 256 + threadIdx.x;
  if (i < n4) {
    float4 v = *(const float4*)(in + i * 4);
    uint2 pk;
    pk.x = bf16bits(v.x) | ((unsigned)bf16bits(v.y) << 16);
    pk.y = bf16bits(v.z) | ((unsigned)bf16bits(v.w) << 16);
    *(uint2*)(out + i * 4) = pk;
  }
}

// concat up to 3 bias vectors of length n into dst (total elements = total).
__global__ __launch_bounds__(256)
void concatb_k(float* dst, const float* a, const float* b, const float* c,
               int n, int total) {
  int i = blockIdx.x * 256 + threadIdx.x;
  if (i >= total) return;
  float v = (i < n) ? a[i] : (i < 2 * n ? b[i - n] : c[i - 2 * n]);
  dst[i] = v;
}

// out[i] = sum of 4 split-K partials + bias (f32). 4M elements, float4/thread.
__global__ __launch_bounds__(256)
void reduce4_k(const float* __restrict__ part, const float* __restrict__ bias,
               float* __restrict__ out) {
  long i = ((long)blockIdx.x * 256 + threadIdx.x) * 4;
  float4 a = *(const float4*)(part + i);
  float4 b = *(const float4*)(part + 4194304 + i);
  float4 c = *(const float4*)(part + 2 * 4194304 + i);
  float4 d = *(const float4*)(part + 3 * 4194304 + i);
  float4 bi = *(const float4*)(bias + (int)(i & 1023));
  float4 o;
  o.x = a.x + b.x + c.x + d.x + bi.x;
  o.y = a.y + b.y + c.y + d.y + bi.y;
  o.z = a.z + b.z + c.z + d.z + bi.z;
  o.w = a.w + b.w + c.w + d.w + bi.w;
  *(float4*)(out + i) = o;
}

static inline GemmP mkp(const void* A, const bf16* Bt, void* C,
                        const float* bias, const int* km, float sc,
                        int M, int N, int K, int lda, int ldb, int ldc,
                        long sAb, long sAh, long sBb, long sBh, long sCb, long sCh) {
  GemmP p;
  p.A = (const bf16*)A; p.Bt = Bt; p.C = C; p.bias = bias; p.kmask = km; p.scale = sc;
  p.M = M; p.N = N; p.K = K; p.lda = lda; p.ldb = ldb; p.ldc = ldc;
  p.sAb = sAb; p.sAh = sAh; p.sBb = sBb; p.sBh = sBh; p.sCb = sCb; p.sCh = sCh;
  return p;
}

extern "C" void kernel_launch(void* const* d_in, const int* in_sizes, int n_in,
                              void* d_out, int out_size, void* d_ws, size_t ws_size,
                              hipStream_t stream) {
  const float* x        = (const float*)d_in[0];
  const float* enc_o    = (const float*)d_in[1];
  const int*   enc_mask = (const int*)d_in[2];
  const float* a1_wq = (const float*)d_in[3];  const float* a1_bq = (const float*)d_in[4];
  const float* a1_wk = (const float*)d_in[5];  const float* a1_bk = (const float*)d_in[6];
  const float* a1_wv = (const float*)d_in[7];  const float* a1_bv = (const float*)d_in[8];
  const float* a1_wo = (const float*)d_in[9];  const float* a1_bo = (const float*)d_in[10];
  const float* a2_wq = (const float*)d_in[11]; const float* a2_bq = (const float*)d_in[12];
  const float* a2_wk = (const float*)d_in[13]; const float* a2_bk = (const float*)d_in[14];
  const float* a2_wv = (const float*)d_in[15]; const float* a2_bv = (const float*)d_in[16];
  const float* a2_wo = (const float*)d_in[17]; const float* a2_bo = (const float*)d_in[18];
  const float* ff_w1 = (const float*)d_in[19]; const float* ff_b1 = (const float*)d_in[20];
  const float* ff_w2 = (const float*)d_in[21]; const float* ff_b2 = (const float*)d_in[22];
  const float* ln1_g = (const float*)d_in[23]; const float* ln1_b = (const float*)d_in[24];
  const float* ln2_g = (const float*)d_in[25]; const float* ln2_b = (const float*)d_in[26];
  const float* ln3_g = (const float*)d_in[27]; const float* ln3_b = (const float*)d_in[28];

  const size_t MB = 1u << 20;
  const long M1 = 1048576;  // elements
  char* w = (char*)d_ws;
  bf16*  xb   = (bf16*)(w + 0);
  bf16*  encb = (bf16*)(w + 8 * MB);
  float* x1f  = (float*)(w + 24 * MB);
  float* x2f  = (float*)(w + 40 * MB);
  bf16*  xcb  = (bf16*)(w + 56 * MB);
  bf16*  wT   = (bf16*)(w + 64 * MB);   // 16M elems = 32MB
  float* bqkv = (float*)(w + 96 * MB);  // [3072]
  float* bkv  = (float*)(w + 96 * MB + 16384);  // [2048]
  bf16*  QKV  = (bf16*)(w + 104 * MB);  // self: [4096,3072]; cross: Qc [4096,1024]
  bf16*  KVc  = (bf16*)(w + 128 * MB);  // cross: [8192,2048]
  bf16*  Vt   = (bf16*)(w + 160 * MB);
  bf16*  Ob   = (bf16*)(w + 176 * MB);
  float* res  = (float*)(w + 184 * MB);
  float* part = (float*)(w + 200 * MB); // 4 x [4096,1024] f32
  bf16*  Asf  = (bf16*)(w + 264 * MB);  // self scores 67MB; FFN hidden 32MB
  bf16*  Pb   = (bf16*)(w + 332 * MB);  // cross probs bf16 [B,H,512,1024]

  float* out_x = (float*)d_out;
  float* attn  = (float*)d_out + 4194304;  // [B,H,512,1024] f32

  const dim3 blk(256);

  // ---- inputs to bf16; all weight transposes up front ----
  cvt_k<<<4096, blk, 0, stream>>>(x, xb, 1048576);
  cvt_k<<<8192, blk, 0, stream>>>(enc_o, encb, 2097152);
  {
    dim3 tg(32, 32, 1);
    transpose_k<float><<<tg, blk, 0, stream>>>(a1_wq, wT + 0 * M1, 1024, 1024, 1024, 1024, 0,0,0,0);
    transpose_k<float><<<tg, blk, 0, stream>>>(a1_wk, wT + 1 * M1, 1024, 1024, 1024, 1024, 0,0,0,0);
    transpose_k<float><<<tg, blk, 0, stream>>>(a1_wv, wT + 2 * M1, 1024, 1024, 1024, 1024, 0,0,0,0);
    transpose_k<float><<<tg, blk, 0, stream>>>(a1_wo, wT + 3 * M1, 1024, 1024, 1024, 1024, 0,0,0,0);
    transpose_k<float><<<tg, blk, 0, stream>>>(a2_wq, wT + 4 * M1, 1024, 1024, 1024, 1024, 0,0,0,0);
    transpose_k<float><<<tg, blk, 0, stream>>>(a2_wk, wT + 5 * M1, 1024, 1024, 1024, 1024, 0,0,0,0);
    transpose_k<float><<<tg, blk, 0, stream>>>(a2_wv, wT + 6 * M1, 1024, 1024, 1024, 1024, 0,0,0,0);
    transpose_k<float><<<tg, blk, 0, stream>>>(a2_wo, wT + 7 * M1, 1024, 1024, 1024, 1024, 0,0,0,0);
    transpose_k<float><<<dim3(128, 32, 1), blk, 0, stream>>>(ff_w1, wT + 8 * M1, 1024, 4096, 4096, 1024, 0,0,0,0);
    transpose_k<float><<<dim3(32, 128, 1), blk, 0, stream>>>(ff_w2, wT + 12 * M1, 4096, 1024, 1024, 4096, 0,0,0,0);
  }
  concatb_k<<<12, blk, 0, stream>>>(bqkv, a1_bq, a1_bk, a1_bv, 1024, 3072);
  concatb_k<<<8, blk, 0, stream>>>(bkv, a2_bk, a2_bv, a2_bv, 1024, 2048);

  // ================= Phase 1: self attention =================
  // fused QKV: [4096,3072] = xb @ [wq|wk|wv]^T   (768 blocks)
  gemm_k<EPI_BIAS_BF16><<<dim3(24, 32, 1), blk, 0, stream>>>(
      mkp(xb, wT, QKV, bqkv, nullptr, 0.f, 4096, 3072, 1024, 1024, 1024, 3072, 0,0,0,0,0,0));
  bf16* Qs = QKV;           // ld 3072
  bf16* Ks = QKV + 1024;
  bf16* Vs = QKV + 2048;

  // S = Q K^T / 8, causal, bf16 -> Asf [B,H,512,512]
  gemm_k<EPI_CAUSAL_BF16><<<dim3(4, 4, 128), blk, 0, stream>>>(
      mkp(Qs, Ks, Asf, nullptr, nullptr, 0.125f, 512, 512, 64, 3072, 3072, 512,
          1572864, 64, 1572864, 64, 4194304, 262144));
  softmax_self_k<<<16384, blk, 0, stream>>>(Asf);

  // V -> Vt [B,H,64,512]
  transpose_k<bf16><<<dim3(2, 16, 128), blk, 0, stream>>>(
      Vs, Vt, 512, 64, 3072, 512, 1572864, 64, 524288, 32768);

  // O = A V -> Ob [4096,1024] head-merged
  gemm_k<EPI_NONE_BF16><<<dim3(1, 4, 128), blk, 0, stream>>>(
      mkp(Asf, Vt, Ob, nullptr, nullptr, 0.f, 512, 64, 512, 512, 512, 1024,
          4194304, 262144, 524288, 32768, 524288, 64));

  // res = O wo + bo (f32)
  gemm_k<EPI_BIAS_F32><<<dim3(8, 32, 1), blk, 0, stream>>>(
      mkp(Ob, wT + 3 * M1, res, a1_bo, nullptr, 0.f, 4096, 1024, 1024, 1024, 1024, 1024, 0,0,0,0,0,0));

  ln_k<<<1024, blk, 0, stream>>>(x, res, ln1_g, ln1_b, x1f, xcb);

  // ================= Phase 2: cross attention =================
  gemm_k<EPI_BIAS_BF16><<<dim3(8, 32, 1), blk, 0, stream>>>(
      mkp(xcb, wT + 4 * M1, QKV, a2_bq, nullptr, 0.f, 4096, 1024, 1024, 1024, 1024, 1024, 0,0,0,0,0,0));
  // fused KV: [8192,2048] = encb @ [wk|wv]^T   (1024 blocks)
  gemm_k<EPI_BIAS_BF16><<<dim3(16, 64, 1), blk, 0, stream>>>(
      mkp(encb, wT + 5 * M1, KVc, bkv, nullptr, 0.f, 8192, 2048, 1024, 1024, 1024, 2048, 0,0,0,0,0,0));
  bf16* Qc = QKV;          // ld 1024
  bf16* Kc = KVc;          // ld 2048
  bf16* Vc = KVc + 1024;

  // S = Q K^T / 8, kv-mask, f32 -> attn (in d_out)
  gemm_k<EPI_KMASK_F32><<<dim3(8, 4, 128), blk, 0, stream>>>(
      mkp(Qc, Kc, attn, nullptr, enc_mask, 0.125f, 512, 1024, 64, 1024, 2048, 1024,
          524288, 64, 2097152, 64, 8388608, 524288));
  softmax_cross_k<<<16384, blk, 0, stream>>>(attn, Pb);

  // V -> Vt [B,H,64,1024]
  transpose_k<bf16><<<dim3(2, 32, 128), blk, 0, stream>>>(
      Vc, Vt, 1024, 64, 2048, 1024, 2097152, 64, 1048576, 65536);

  // O = P V (bf16 sidecar) -> Ob
  gemm_k<EPI_NONE_BF16><<<dim3(1, 4, 128), blk, 0, stream>>>(
      mkp(Pb, Vt, Ob, nullptr, nullptr, 0.f, 512, 64, 1024, 1024, 1024, 1024,
          8388608, 524288, 1048576, 65536, 524288, 64));

  gemm_k<EPI_BIAS_F32><<<dim3(8, 32, 1), blk, 0, stream>>>(
      mkp(Ob, wT + 7 * M1, res, a2_bo, nullptr, 0.f, 4096, 1024, 1024, 1024, 1024, 1024, 0,0,0,0,0,0));

  ln_k<<<1024, blk, 0, stream>>>(x1f, res, ln2_g, ln2_b, x2f, xcb);

  // ================= Phase 3: FFN =================
  gemm_k<EPI_BIAS_RELU_BF16><<<dim3(32, 32, 1), blk, 0, stream>>>(
      mkp(xcb, wT + 8 * M1, Asf, ff_b1, nullptr, 0.f, 4096, 4096, 1024, 1024, 1024, 4096, 0,0,0,0,0,0));
  // FFN2 split-K=4: z=0..3 selects K-slice via "head" strides (zb=0, zh=z)
  gemm_k<EPI_PART_F32><<<dim3(8, 32, 4), blk, 0, stream>>>(
      mkp(Asf, wT + 12 * M1, part, nullptr, nullptr, 0.f, 4096, 1024, 1024, 4096, 4096, 1024,
          0, 1024, 0, 1024, 0, 4194304));
  reduce4_k<<<4096, blk, 0, stream>>>(part, ff_b2, res);

  ln_k<<<1024, blk, 0, stream>>>(x2f, res, ln3_g, ln3_b, out_x, nullptr);
}